// Round 4
// baseline (190.387 us; speedup 1.0000x reference)
//
#include <hip/hip_runtime.h>
#include <math.h>

#define S_LEN 8192
#define DHEAD 64
#define NBATCH 4
#define BQ 128
#define BK 32
#define KIT 64            // 2048 keys per kq-quarter / BK

typedef unsigned short u16;
typedef unsigned int u32;
typedef __attribute__((ext_vector_type(8))) short short8;
typedef __attribute__((ext_vector_type(4))) float f32x4;

union U16x8 { int4 i4; short8 s8; u32 w[4]; };

#if __has_builtin(__builtin_amdgcn_exp2f)
#define EXP2(x) __builtin_amdgcn_exp2f(x)
#else
#define EXP2(x) exp2f(x)
#endif

// float -> bf16 RNE (prep path only)
__device__ __forceinline__ u16 f2b(float f) {
    u32 u = __float_as_uint(f);
    u32 r = (u + 0x7fffu + ((u >> 16) & 1u)) >> 16;
    return (u16)r;
}

// two floats -> packed bf16x2 (a low), round-half-up: 2 add + 1 perm
__device__ __forceinline__ u32 pack2(float a, float b) {
    u32 ua = __float_as_uint(a) + 0x8000u;
    u32 ub = __float_as_uint(b) + 0x8000u;
    return __builtin_amdgcn_perm(ub, ua, 0x07060302u);
}

__device__ __forceinline__ void load_lds16(const u16* g, u16* l) {
    __builtin_amdgcn_global_load_lds(
        (const __attribute__((address_space(1))) u32*)g,
        (__attribute__((address_space(3))) u32*)l, 16, 0, 0);
}

// K LDS row swizzle: 3 bits of row entropy into the 8-granule index
__device__ __forceinline__ int swzK(int r) { return (r & 3) | ((r >> 1) & 4); }
// V LDS row swizzle: 2 bits into the 4-granule index
__device__ __forceinline__ int swzV(int d) { return (d & 3) ^ ((d >> 2) & 3); }

// ---------------------------------------------------------------------------
// Fused prep: [0,512) V->Vt bf16 [b][d][s] (plain layout; swizzles applied at
// LDS-stage time in flash); [512,1024) K->bf16; [1024,1056) Julia bias in f64
// (matches numpy), with fixed softmax max M=20 folded in.
// ---------------------------------------------------------------------------
__global__ void prep_kernel(const float* __restrict__ K, const float* __restrict__ V,
                            const float* crp, const float* cip, const float* scp,
                            u16* __restrict__ Kb, u16* __restrict__ Vt,
                            float* __restrict__ bias2) {
    int bid = blockIdx.x, tid = threadIdx.x;
    if (bid < 512) {
        __shared__ float tile[64][65];
        int b = bid >> 7;
        int s0 = (bid & 127) * 64;
        int c4 = (tid & 15) * 4;
        int rr = tid >> 4;
#pragma unroll
        for (int p = 0; p < 4; ++p) {
            int row = p * 16 + rr;
            float4 v = *(const float4*)(V + ((size_t)(b * S_LEN + s0 + row)) * DHEAD + c4);
            tile[row][c4 + 0] = v.x; tile[row][c4 + 1] = v.y;
            tile[row][c4 + 2] = v.z; tile[row][c4 + 3] = v.w;
        }
        __syncthreads();
#pragma unroll
        for (int p = 0; p < 4; ++p) {
            int d = p * 16 + rr;
            u32 lo = (u32)f2b(tile[c4 + 0][d]) | ((u32)f2b(tile[c4 + 1][d]) << 16);
            u32 hi = (u32)f2b(tile[c4 + 2][d]) | ((u32)f2b(tile[c4 + 3][d]) << 16);
            *(uint2*)(Vt + ((size_t)(b * DHEAD + d)) * S_LEN + s0 + c4) = make_uint2(lo, hi);
        }
    } else if (bid < 1024) {
        size_t base = ((size_t)(bid - 512) * 256 + tid) * 16;
#pragma unroll
        for (int j = 0; j < 4; ++j) {
            float4 v = *(const float4*)(K + base + j * 4);
            u32 lo = (u32)f2b(v.x) | ((u32)f2b(v.y) << 16);
            u32 hi = (u32)f2b(v.z) | ((u32)f2b(v.w) << 16);
            *(uint2*)(Kb + base + j * 4) = make_uint2(lo, hi);
        }
    } else {
#pragma clang fp contract(off)
        int i = (bid - 1024) * 256 + tid;
        double cr = (double)crp[0], ci = (double)cip[0], sc = (double)scp[0];
        double step = 4.0 / (double)(S_LEN - 1);
        double x = (i == S_LEN - 1) ? 2.0 : (-2.0 + step * (double)i);
        double zr = x, zi = 0.0, et = 1.0;
        bool esc = false;
        for (int it = 0; it < 64; ++it) {
            double nzr = zr * zr - zi * zi + cr;
            double nzi = 2.0 * zr * zi + ci;
            if (!esc) { zr = nzr; zi = nzi; }
            double m2 = zr * zr + zi * zi;
            if (!esc && m2 > 4.0) { et = (double)it / 64.0; esc = true; }
        }
        double bias = log(exp(et * sc) + 1e-8);
        bias2[i] = (float)(bias * 1.4426950408889634 - 20.0);
    }
}

// ---------------------------------------------------------------------------
// Flash, 64 q-rows/wave, fixed-max softmax, 4-way in-block split-K:
//   grid 256 (1 block/CU), block 512 = 8 waves = 4 kq x 2 qs; wave: 64 q x
//   2048 keys, BK=32, dbuf LDS, 1 barrier/iter.
//   QK tiles use key-permuted rows (key = 8*(m>>2)+4*kt+(m&3)) so the P
//   C-frag IS the 16x16x32 B-operand layout -> PV in K=32 with b128 V reads.
// ---------------------------------------------------------------------------
__global__ __launch_bounds__(512, 2)
void flash_kernel(const float* __restrict__ Q, const u16* __restrict__ Kb,
                  const u16* __restrict__ Vt, const float* __restrict__ bias2,
                  float* __restrict__ Out) {
    __shared__ __align__(16) char smem[65536];
    u16* K_lds = (u16*)smem;            // [buf][kq][32 r][8 gph][8] u16, buf stride 8192
    u16* V_lds = (u16*)(smem + 32768);  // [buf][kq][64 d][4 gph][8] u16

    const int tid = threadIdx.x;
    const int w = tid >> 6, l = tid & 63, low = l & 15, h = l >> 4;
    const int kq = w & 3, qs = w >> 2;

    const int bid = blockIdx.x;
    const int batch = bid & 3;          // XCD-affinity: 2 XCDs per batch
    const int qtile = bid >> 2;         // 0..63
    const int q0 = qtile * BQ + qs * 64;

    // ---- Q fragments (4 x 16 q-rows), scale log2(e)/8 folded ----
    const float qscale = 0.18033688011112042f;
    short8 qfrag[4][2];
#pragma unroll
    for (int qf = 0; qf < 4; ++qf) {
        const float* qrow = Q + ((size_t)(batch * S_LEN + q0 + qf * 16 + low)) * DHEAD + h * 8;
#pragma unroll
        for (int ds = 0; ds < 2; ++ds) {
            f32x4 a = *(const f32x4*)(qrow + ds * 32);
            f32x4 b = *(const f32x4*)(qrow + ds * 32 + 4);
            U16x8 u;
#pragma unroll
            for (int j = 0; j < 4; ++j) {
                u.s8[j]     = (short)f2b(a[j] * qscale);
                u.s8[4 + j] = (short)f2b(b[j] * qscale);
            }
            qfrag[qf][ds] = u.s8;
        }
    }

    // ---- staging map: thread stages granules tid and tid+512 of each tile ----
    const u16 *kp0, *kp1, *vp0, *vp1;
    {
        int kqs = tid >> 8, r = (tid >> 3) & 31, gph = tid & 7;
        int gl = gph ^ swzK(r);
        kp0 = Kb + ((size_t)(batch * S_LEN + kqs * 2048 + r)) * 64 + gl * 8;
        kp1 = kp0 + (size_t)2 * 2048 * 64;      // granule tid+512 -> kq+2
        int dv = (tid >> 2) & 63, gphv = tid & 3;
        int glv = gphv ^ swzV(dv);
        vp0 = Vt + ((size_t)(batch * DHEAD + dv)) * S_LEN + kqs * 2048 + glv * 8;
        vp1 = vp0 + 2 * 2048;
    }
    const int dst0 = tid * 8, dst1 = tid * 8 + 4096;   // u16 elems within buf

    // stage tile 0 into buf 0
    load_lds16(kp0, K_lds + dst0);
    load_lds16(kp1, K_lds + dst1);
    load_lds16(vp0, V_lds + dst0);
    load_lds16(vp1, V_lds + dst1);
    kp0 += BK * DHEAD; kp1 += BK * DHEAD; vp0 += BK; vp1 += BK;

    // ---- loop-invariant LDS read offsets (u16 elems) ----
    int koff[2][2], voff[4];
#pragma unroll
    for (int kt = 0; kt < 2; ++kt) {
        const int R = 8 * (low >> 2) + 4 * kt + (low & 3);   // key-permuted row
#pragma unroll
        for (int ds = 0; ds < 2; ++ds)
            koff[kt][ds] = kq * 2048 + R * 64 + (((ds * 4 + h) ^ swzK(R)) * 8);
    }
#pragma unroll
    for (int dt = 0; dt < 4; ++dt) {
        const int d = dt * 16 + low;
        voff[dt] = kq * 2048 + d * 32 + ((h ^ swzV(d)) * 8);
    }

    f32x4 o[4][4];
#pragma unroll
    for (int qf = 0; qf < 4; ++qf)
#pragma unroll
        for (int dt = 0; dt < 4; ++dt) o[qf][dt] = (f32x4){0, 0, 0, 0};
    float lsum[4] = {0.f, 0.f, 0.f, 0.f};

    // bias pipeline: bias2[key], key = kq*2048 + ki*32 + 8h + 4kt + r
    const float* b2p = bias2 + kq * 2048 + h * 8;
    f32x4 bv0 = *(const f32x4*)b2p;
    f32x4 bv1 = *(const f32x4*)(b2p + 4);
    b2p += BK;

    for (int ki = 0; ki < KIT; ++ki) {
        __syncthreads();               // buf[ki&1] staged; prior reads done
        const int pb = ki & 1;
        if (ki != KIT - 1) {
            const int db = (pb ^ 1) * 8192;
            load_lds16(kp0, K_lds + db + dst0);
            load_lds16(kp1, K_lds + db + dst1);
            load_lds16(vp0, V_lds + db + dst0);
            load_lds16(vp1, V_lds + db + dst1);
            kp0 += BK * DHEAD; kp1 += BK * DHEAD; vp0 += BK; vp1 += BK;
        }
        // prefetch next iter's bias (reads ≤128B past quarter end on last
        // iter — lands in Kb region, unused)
        f32x4 bvn0 = *(const f32x4*)b2p;
        f32x4 bvn1 = *(const f32x4*)(b2p + 4);
        b2p += BK;

        const u16* kb = K_lds + pb * 8192;
        const u16* vb = V_lds + pb * 8192;

        // ---- S^T = K·Q^T + bias (C-init); K-frag shared across 4 q-frags ----
        f32x4 st[4][2];
#pragma unroll
        for (int kt = 0; kt < 2; ++kt) {
            U16x8 k0, k1;
            k0.i4 = *(const int4*)&kb[koff[kt][0]];
            k1.i4 = *(const int4*)&kb[koff[kt][1]];
            const f32x4 binit = kt ? bv1 : bv0;
#pragma unroll
            for (int qf = 0; qf < 4; ++qf) {
                f32x4 a = __builtin_amdgcn_mfma_f32_16x16x32_bf16(k0.s8, qfrag[qf][0], binit, 0, 0, 0);
                a = __builtin_amdgcn_mfma_f32_16x16x32_bf16(k1.s8, qfrag[qf][1], a, 0, 0, 0);
                st[qf][kt] = a;
            }
        }
        bv0 = bvn0; bv1 = bvn1;

        // ---- fixed-max softmax: p = exp2(score); pack into x32 B-frags ----
        U16x8 pf[4];
#pragma unroll
        for (int qf = 0; qf < 4; ++qf) {
#pragma unroll
            for (int kt = 0; kt < 2; ++kt) {
                float p0 = EXP2(st[qf][kt][0]), p1 = EXP2(st[qf][kt][1]);
                float p2 = EXP2(st[qf][kt][2]), p3 = EXP2(st[qf][kt][3]);
                lsum[qf] += (p0 + p1) + (p2 + p3);
                pf[qf].w[kt * 2]     = pack2(p0, p1);
                pf[qf].w[kt * 2 + 1] = pack2(p2, p3);
            }
        }

        // ---- O^T += V^T·P^T (K=32): V-frag b128, shared across 4 q-frags ----
#pragma unroll
        for (int dt = 0; dt < 4; ++dt) {
            U16x8 vf;
            vf.i4 = *(const int4*)&vb[voff[dt]];
#pragma unroll
            for (int qf = 0; qf < 4; ++qf)
                o[qf][dt] = __builtin_amdgcn_mfma_f32_16x16x32_bf16(vf.s8, pf[qf].s8, o[qf][dt], 0, 0, 0);
        }
    }

    // ---- finalize l (one cross-lane reduce per q-frag) ----
#pragma unroll
    for (int qf = 0; qf < 4; ++qf) {
        lsum[qf] += __shfl_xor(lsum[qf], 16, 64);
        lsum[qf] += __shfl_xor(lsum[qf], 32, 64);
    }

    // ---- split-K merge: partials add linearly (fixed max). 3 stages. ----
    float* MO = (float*)smem;              // [128][68]
    float* ML = (float*)(smem + 34816);    // [128]
    const int baserow = qs * 64 + low;
#pragma unroll 1
    for (int src = 1; src < 4; ++src) {
        __syncthreads();
        if (kq == src) {
#pragma unroll
            for (int qf = 0; qf < 4; ++qf) {
                const int row = baserow + qf * 16;
#pragma unroll
                for (int dt = 0; dt < 4; ++dt)
                    *(f32x4*)&MO[row * 68 + dt * 16 + h * 4] = o[qf][dt];
                if (h == 0) ML[row] = lsum[qf];
            }
        }
        __syncthreads();
        if (kq == 0) {
#pragma unroll
            for (int qf = 0; qf < 4; ++qf) {
                const int row = baserow + qf * 16;
#pragma unroll
                for (int dt = 0; dt < 4; ++dt) {
                    f32x4 a = *(const f32x4*)&MO[row * 68 + dt * 16 + h * 4];
#pragma unroll
                    for (int j = 0; j < 4; ++j) o[qf][dt][j] += a[j];
                }
                lsum[qf] += ML[row];
            }
        }
    }

    if (kq == 0) {
#pragma unroll
        for (int qf = 0; qf < 4; ++qf) {
            const float inv = 1.f / lsum[qf];
            float* orow = Out + ((size_t)(batch * S_LEN + qtile * BQ + qs * 64 + qf * 16 + low)) * DHEAD;
#pragma unroll
            for (int dt = 0; dt < 4; ++dt) {
                f32x4 r;
#pragma unroll
                for (int j = 0; j < 4; ++j) r[j] = o[qf][dt][j] * inv;
                *(f32x4*)(orow + dt * 16 + h * 4) = r;
            }
        }
    }
}

// ---------------------------------------------------------------------------
extern "C" void kernel_launch(void* const* d_in, const int* in_sizes, int n_in,
                              void* d_out, int out_size, void* d_ws, size_t ws_size,
                              hipStream_t stream) {
    const float* Q  = (const float*)d_in[0];
    const float* K  = (const float*)d_in[1];
    const float* V  = (const float*)d_in[2];
    const float* cr = (const float*)d_in[3];
    const float* ci = (const float*)d_in[4];
    const float* sc = (const float*)d_in[5];
    float* out = (float*)d_out;

    char* ws = (char*)d_ws;
    float* bias2 = (float*)ws;                                    // 32 KB (+pad)
    u16*   Kb    = (u16*)(ws + 32768);                            // 4 MB
    u16*   Vt    = (u16*)(ws + 32768 + (size_t)NBATCH * S_LEN * DHEAD * 2);

    prep_kernel<<<dim3(1056), dim3(256), 0, stream>>>(K, V, cr, ci, sc, Kb, Vt, bias2);
    flash_kernel<<<dim3(256), dim3(512), 0, stream>>>(Q, Kb, Vt, bias2, out);
}